// Round 4
// baseline (1169.523 us; speedup 1.0000x reference)
//
#include <hip/hip_runtime.h>

// LSTM_26912265077001: 2-layer LSTM (H=51, IN=1), T=512, B=1024, fp32.
//
// V5: gate-aligned MFMA tiles + in-register elementwise + 1 barrier/iter.
//  - NB=16 batches/block (fills the MFMA M dim; V4 used 4/16 rows), 64 blocks.
//  - B-fragments use CUSTOM row sets: for j-group j0, the 4 tiles are gate
//    rows {g*51 + j0 + m}, g = i,f,g,o.  After MFMA, lane (m,ch) reg r holds
//    the full (i,f,g,o) quad for (batch 4ch+r, unit j0+m) -> sigmoid/tanh/
//    cell-update entirely in registers.  No gate LDS arrays at all.
//  - Unified A operand [h1(0..50) | x(51) | 0 | h2(64..114) | 0], bf16 hi/lo,
//    double-buffered by parity.  L1 reads ksteps 0-1, L2 reads ksteps 0-3
//    (B2 rows are zero for k=51..63,115..127 so x/pad can't pollute L2).
//  - 3-term split product (AhBh + AlBh + AhBl; AlBl ~2^-18 dropped).
//  - 8 waves: waves 0-3 = L1 (j-groups 0..3) + y-dot + x-staging;
//    waves 4-7 = L2 (j-groups 0..3).  One __syncthreads per iteration:
//    every read in iter 'it' is of data written in iter it-1 (parity flip).
//  - Pipeline: iter it: L1 -> h1[it] (it<Ts); L2 -> h2[it-1] (1<=it<=Ts);
//    y[it-2] (it>=2).  Loop to it=Ts+1 to drain y.
//
// MFMA 16x16x32 bf16 maps (m89-verified, V4-validated):
//   A: row(batch) = lane&15, k = (lane>>4)*8 + j
//   B: col(unit)  = lane&15, k = (lane>>4)*8 + j
//   D: col(unit)  = lane&15, row(batch) = (lane>>4)*4 + reg

#define Hs    51
#define Ts    512
#define Bs    1024
#define NB    16
#define NT    512
#define SA    136        // A row stride in ushorts (272B, 16B-aligned)
#define XCOL  51
#define H2COL 64

typedef __attribute__((ext_vector_type(8))) short bf16x8;
typedef __attribute__((ext_vector_type(4))) float f32x4;
typedef unsigned short u16;

__device__ __forceinline__ float sig_(float x)  { return 1.0f / (1.0f + __expf(-x)); }
__device__ __forceinline__ float tanh_(float x) { float e = __expf(2.0f * x); return 1.0f - 2.0f / (e + 1.0f); }
__device__ __forceinline__ u16 bfh_(float x) {   // fp32 -> bf16 (RNE)
    unsigned u = __float_as_uint(x);
    return (u16)((u + 0x7FFFu + ((u >> 16) & 1u)) >> 16);
}
__device__ __forceinline__ float bff_(u16 h) { return __uint_as_float(((unsigned)h) << 16); }

__global__ __launch_bounds__(NT, 2) void lstm2_kernel(
    const float* __restrict__ x,      // (T, B, 1)
    const float* __restrict__ W_ih1,  // (204, 1)
    const float* __restrict__ W_hh1,  // (204, 51)
    const float* __restrict__ b_ih1,  // (204,)
    const float* __restrict__ b_hh1,  // (204,)
    const float* __restrict__ W_ih2,  // (204, 51)
    const float* __restrict__ W_hh2,  // (204, 51)
    const float* __restrict__ b_ih2,  // (204,)
    const float* __restrict__ b_hh2,  // (204,)
    const float* __restrict__ W_lin,  // (1, 51)
    const float* __restrict__ b_lin,  // (1,)
    float* __restrict__ out)          // (B, T)
{
    __shared__ __align__(16) u16   Ah[2][NB * SA];   // A operand hi (parity)
    __shared__ __align__(16) u16   Al[2][NB * SA];   // A operand lo
    __shared__ __align__(16) float xs[Ts][NB];       // 32 KB input slice
    __shared__ __align__(16) float h2f[2][NB][68];   // fp32 h2 (for exact y)
    __shared__ __align__(16) float wlin_s[64];
    __shared__ float blin_sh;

    const int tid  = threadIdx.x;
    const int lane = tid & 63;
    const int wv   = tid >> 6;         // 0..7
    const int role = wv >> 2;          // 0 = L1, 1 = L2
    const int jg   = wv & 3;           // j-group
    const int j0   = jg * 16;
    const int m    = lane & 15;        // unit-within-tile / A batch row
    const int ch   = lane >> 4;        // k-chunk / batch group
    const int bg0  = blockIdx.x * NB;
    const int nks  = role ? 4 : 2;     // ksteps (L1: K=64, L2: K=128)

    // ---- one-time init ----
    for (int i = tid; i < Ts * NB; i += NT) {
        int t = i >> 4, b = i & 15;
        xs[t][b] = x[t * Bs + bg0 + b];
    }
    for (int i = tid; i < 2 * NB * SA; i += NT) {
        ((u16*)Ah)[i] = 0;
        ((u16*)Al)[i] = 0;
    }
    for (int i = tid; i < 2 * NB * 68; i += NT) ((float*)h2f)[i] = 0.f;
    if (tid < 64) wlin_s[tid] = (tid < Hs) ? W_lin[tid] : 0.f;
    if (tid == 0) blin_sh = b_lin[0];
    if (tid < NB) {                    // x[0] into parity 1 (read at it=0)
        float xv = x[bg0 + tid];
        u16 hh = bfh_(xv);
        Ah[1][tid * SA + XCOL] = hh;
        Al[1][tid * SA + XCOL] = bfh_(xv - bff_(hh));
    }

    // ---- B-fragments: 4 gate-tiles x up-to-4 ksteps, hi/lo ----
    const int  jrow = j0 + m;          // unit index 0..63 (valid < 51)
    const bool rv   = jrow < Hs;
    bf16x8 Bh[4][4], Bl[4][4];
    float  bias[4];
    #pragma unroll
    for (int g = 0; g < 4; ++g) {
        const int row = g * Hs + jrow; // gate row in the 204-row matrix
        bias[g] = 0.f;
        if (rv) bias[g] = role ? (b_ih2[row] + b_hh2[row])
                               : (b_ih1[row] + b_hh1[row]);
        #pragma unroll
        for (int s = 0; s < 4; ++s) {
            bf16x8 h8 = {0,0,0,0,0,0,0,0};
            bf16x8 l8 = {0,0,0,0,0,0,0,0};
            if (s < nks) {
                #pragma unroll
                for (int j = 0; j < 8; ++j) {
                    const int k = s * 32 + ch * 8 + j;
                    float v = 0.f;
                    if (rv) {
                        if (role == 0) {
                            if (k < Hs)        v = W_hh1[row * Hs + k];
                            else if (k == XCOL) v = W_ih1[row];
                        } else {
                            if (k < Hs)                          v = W_ih2[row * Hs + k];
                            else if (k >= H2COL && k < H2COL + Hs) v = W_hh2[row * Hs + (k - H2COL)];
                        }
                    }
                    u16 hh = bfh_(v);
                    h8[j] = (short)hh;
                    l8[j] = (short)bfh_(v - bff_(hh));
                }
            }
            Bh[g][s] = h8;
            Bl[g][s] = l8;
        }
    }

    float c_[4] = {0.f, 0.f, 0.f, 0.f};   // cell state: batch 4ch+r, unit jrow
    __syncthreads();

    for (int it = 0; it <= Ts + 1; ++it) {
        const int  pR   = (it - 1) & 1;
        const int  pW   = it & 1;
        const bool doL1 = (role == 0) && (it < Ts);
        const bool doL2 = (role == 1) && (it >= 1) && (it <= Ts);

        if (doL1 || doL2) {
            // A-fragments (lane m reads batch m's row)
            bf16x8 Ah_[4], Al_[4];
            #pragma unroll
            for (int s = 0; s < 4; ++s) if (s < nks) {
                Ah_[s] = *(const bf16x8*)&Ah[pR][m * SA + s * 32 + ch * 8];
                Al_[s] = *(const bf16x8*)&Al[pR][m * SA + s * 32 + ch * 8];
            }
            // 4 independent gate chains (i,f,g,o), 3-term split each kstep
            f32x4 acc[4];
            #pragma unroll
            for (int g = 0; g < 4; ++g) {
                f32x4 a = {bias[g], bias[g], bias[g], bias[g]};
                #pragma unroll
                for (int s = 0; s < 4; ++s) if (s < nks) {
                    a = __builtin_amdgcn_mfma_f32_16x16x32_bf16(Ah_[s], Bl[g][s], a, 0, 0, 0);
                    a = __builtin_amdgcn_mfma_f32_16x16x32_bf16(Al_[s], Bh[g][s], a, 0, 0, 0);
                    a = __builtin_amdgcn_mfma_f32_16x16x32_bf16(Ah_[s], Bh[g][s], a, 0, 0, 0);
                }
                acc[g] = a;
            }
            // in-register elementwise update (lane reg r = batch 4ch+r)
            #pragma unroll
            for (int r = 0; r < 4; ++r) {
                float iv = sig_ (acc[0][r]);
                float fv = sig_ (acc[1][r]);
                float gv = tanh_(acc[2][r]);
                float ov = sig_ (acc[3][r]);
                c_[r] = fmaf(fv, c_[r], iv * gv);
                float hv = ov * tanh_(c_[r]);
                if (rv) {
                    const int b = 4 * ch + r;
                    u16 hh = bfh_(hv);
                    u16 hl = bfh_(hv - bff_(hh));
                    if (role == 0) {
                        Ah[pW][b * SA + jrow] = hh;
                        Al[pW][b * SA + jrow] = hl;
                    } else {
                        Ah[pW][b * SA + H2COL + jrow] = hh;
                        Al[pW][b * SA + H2COL + jrow] = hl;
                        h2f[(it - 1) & 1][b][jrow] = hv;   // exact h2 for y
                    }
                }
            }
        }

        // x[it+1] staging into parity pW (read next iter); wave 0, 16 lanes
        if (role == 0 && jg == 0 && lane < NB && (it + 1) < Ts) {
            float xv = xs[it + 1][lane];
            u16 hh = bfh_(xv);
            Ah[pW][lane * SA + XCOL] = hh;
            Al[pW][lane * SA + XCOL] = bfh_(xv - bff_(hh));
        }

        // y[it-2] = W_lin . h2[it-2] + b  (L1 waves; batch = 4*jg + ch)
        if (role == 0 && it >= 2) {
            const float* hp = &h2f[it & 1][4 * jg + ch][0];
            float s = wlin_s[m]      * hp[m]
                    + wlin_s[m + 16] * hp[m + 16]
                    + wlin_s[m + 32] * hp[m + 32]
                    + wlin_s[m + 48] * hp[m + 48];     // pads are zero
            s += __shfl_xor(s, 1);
            s += __shfl_xor(s, 2);
            s += __shfl_xor(s, 4);
            s += __shfl_xor(s, 8);
            if (m == 0) out[(bg0 + 4 * jg + ch) * Ts + (it - 2)] = s + blin_sh;
        }
        __syncthreads();
    }
}

extern "C" void kernel_launch(void* const* d_in, const int* in_sizes, int n_in,
                              void* d_out, int out_size, void* d_ws, size_t ws_size,
                              hipStream_t stream) {
    const float* x     = (const float*)d_in[0];
    const float* W_ih1 = (const float*)d_in[1];
    const float* W_hh1 = (const float*)d_in[2];
    const float* b_ih1 = (const float*)d_in[3];
    const float* b_hh1 = (const float*)d_in[4];
    const float* W_ih2 = (const float*)d_in[5];
    const float* W_hh2 = (const float*)d_in[6];
    const float* b_ih2 = (const float*)d_in[7];
    const float* b_hh2 = (const float*)d_in[8];
    const float* W_lin = (const float*)d_in[9];
    const float* b_lin = (const float*)d_in[10];
    float* out = (float*)d_out;

    lstm2_kernel<<<Bs / NB, NT, 0, stream>>>(
        x, W_ih1, W_hh1, b_ih1, b_hh1,
        W_ih2, W_hh2, b_ih2, b_hh2, W_lin, b_lin, out);
}

// Round 6
// 1036.964 us; speedup vs baseline: 1.1278x; 1.1278x over previous
//
#include <hip/hip_runtime.h>

// LSTM_26912265077001: 2-layer LSTM (H=51, IN=1), T=512, B=1024, fp32.
//
// V7 = V6 with the init-phase LDS race fixed.
// V6 post-mortem: determinism tripwire (direct launch vs graph replay
// diverged). Root cause: x[0] staging into Ah[1]/Al[1] by threads 0..15
// raced the zero-fill loop (same LDS words zeroed by DIFFERENT threads,
// no barrier between). Latent since V4; V6's codegen change flipped the
// schedule. Fix: zero-fill -> barrier -> x[0] staging -> barrier.
//
// V6 design (unchanged, untested perf-wise due to the tripwire):
//  - ALL fragments / accumulators / biases / cell states individually
//    NAMED; loops hand-unrolled. No arrays -> no scratch demotion.
//  - Role paths are two fully separate main loops (wave-aligned split,
//    equal barrier counts) so L1 (~130 regs) and L2 (~200 regs) live
//    sets don't coexist: allocation = max, not sum. Cap 256.
//
// Layout (V5, m89-verified MFMA maps):
//  - NB=16 batches/block, 64 blocks, 8 waves: waves 0-3 L1 (j-groups),
//    waves 4-7 L2. Gate-aligned B tiles: for j-group j0, tiles are gate
//    rows {g*51 + j0 + m}; after MFMA lane (m,ch) reg r holds the full
//    (i,f,g,o) quad for (batch 4ch+r, unit j0+m) -> elementwise in regs.
//  - A operand [h1(0..50) | x(51) | 0 | h2(64..114) | 0] bf16 hi/lo,
//    parity double-buffered. L1 K=64 (2 ksteps), L2 K=128 (4 ksteps).
//  - 3-term split product (AhBl + AlBh + AhBh), 1 barrier/iter.
//  - Pipeline: it: L1->h1[it] (it<Ts); L2->h2[it-1] (1<=it<=Ts);
//    y[it-2] (it>=2); loop to Ts+1 to drain.

#define Hs    51
#define Ts    512
#define Bs    1024
#define NB    16
#define NT    512
#define SA    136        // A row stride in ushorts (272B, 16B-aligned)
#define XCOL  51
#define H2COL 64

typedef __attribute__((ext_vector_type(8))) short bf16x8;
typedef __attribute__((ext_vector_type(4))) float f32x4;
typedef unsigned short u16;

__device__ __forceinline__ float sig_(float x)  { return 1.0f / (1.0f + __expf(-x)); }
__device__ __forceinline__ float tanh_(float x) { float e = __expf(2.0f * x); return 1.0f - 2.0f / (e + 1.0f); }
__device__ __forceinline__ u16 bfh_(float x) {   // fp32 -> bf16 (RNE)
    unsigned u = __float_as_uint(x);
    return (u16)((u + 0x7FFFu + ((u >> 16) & 1u)) >> 16);
}
__device__ __forceinline__ float bff_(u16 h) { return __uint_as_float(((unsigned)h) << 16); }

struct FragHL { bf16x8 h; bf16x8 l; };

// B1 fragment: row of [W_hh1 | W_ih1] at K-step ks, chunk ch.
__device__ __forceinline__ FragHL mkB1(const float* __restrict__ Whh1,
                                       const float* __restrict__ Wih1,
                                       int row, bool rv, int ks, int ch) {
    bf16x8 h = {0,0,0,0,0,0,0,0}, l = {0,0,0,0,0,0,0,0};
    #pragma unroll
    for (int j = 0; j < 8; ++j) {
        const int k = ks * 32 + ch * 8 + j;
        float v = 0.f;
        if (rv) {
            if (k < Hs)         v = Whh1[row * Hs + k];
            else if (k == XCOL) v = Wih1[row];
        }
        u16 hh = bfh_(v);
        h[j] = (short)hh;
        l[j] = (short)bfh_(v - bff_(hh));
    }
    FragHL r; r.h = h; r.l = l; return r;
}

// B2 fragment: row of [W_ih2 | 0 | W_hh2 | 0] at K-step ks, chunk ch.
__device__ __forceinline__ FragHL mkB2(const float* __restrict__ Wih2,
                                       const float* __restrict__ Whh2,
                                       int row, bool rv, int ks, int ch) {
    bf16x8 h = {0,0,0,0,0,0,0,0}, l = {0,0,0,0,0,0,0,0};
    #pragma unroll
    for (int j = 0; j < 8; ++j) {
        const int k = ks * 32 + ch * 8 + j;
        float v = 0.f;
        if (rv) {
            if (k < Hs)                              v = Wih2[row * Hs + k];
            else if (k >= H2COL && k < H2COL + Hs)   v = Whh2[row * Hs + (k - H2COL)];
        }
        u16 hh = bfh_(v);
        h[j] = (short)hh;
        l[j] = (short)bfh_(v - bff_(hh));
    }
    FragHL r; r.h = h; r.l = l; return r;
}

// 3-term split-product accumulate, same term order as V5 (numerics identical)
#define MF(ACC, AFH, AFL, BF)                                                  \
    ACC = __builtin_amdgcn_mfma_f32_16x16x32_bf16(AFH, (BF).l, ACC, 0, 0, 0);  \
    ACC = __builtin_amdgcn_mfma_f32_16x16x32_bf16(AFL, (BF).h, ACC, 0, 0, 0);  \
    ACC = __builtin_amdgcn_mfma_f32_16x16x32_bf16(AFH, (BF).h, ACC, 0, 0, 0);

__global__ __launch_bounds__(NT, 2) void lstm2_kernel(
    const float* __restrict__ x,      // (T, B, 1)
    const float* __restrict__ W_ih1,  // (204, 1)
    const float* __restrict__ W_hh1,  // (204, 51)
    const float* __restrict__ b_ih1,  // (204,)
    const float* __restrict__ b_hh1,  // (204,)
    const float* __restrict__ W_ih2,  // (204, 51)
    const float* __restrict__ W_hh2,  // (204, 51)
    const float* __restrict__ b_ih2,  // (204,)
    const float* __restrict__ b_hh2,  // (204,)
    const float* __restrict__ W_lin,  // (1, 51)
    const float* __restrict__ b_lin,  // (1,)
    float* __restrict__ out)          // (B, T)
{
    __shared__ __align__(16) u16   Ah[2][NB * SA];
    __shared__ __align__(16) u16   Al[2][NB * SA];
    __shared__ __align__(16) float xs[Ts][NB];
    __shared__ __align__(16) float h2f[2][NB][68];
    __shared__ __align__(16) float wlin_s[64];
    __shared__ float blin_sh;

    const int tid  = threadIdx.x;
    const int lane = tid & 63;
    const int wv   = tid >> 6;         // 0..7
    const int role = wv >> 2;          // 0 = L1, 1 = L2
    const int jg   = wv & 3;
    const int m    = lane & 15;
    const int ch   = lane >> 4;
    const int bg0  = blockIdx.x * NB;
    const int  jrow = jg * 16 + m;     // unit index (valid < 51)
    const bool rv   = jrow < Hs;

    // ---- one-time init: zero / preload (NO staging writes yet) ----
    for (int i = tid; i < Ts * NB; i += NT) {
        int t = i >> 4, b = i & 15;
        xs[t][b] = x[t * Bs + bg0 + b];
    }
    for (int i = tid; i < 2 * NB * SA; i += NT) {
        ((u16*)Ah)[i] = 0;
        ((u16*)Al)[i] = 0;
    }
    for (int i = tid; i < 2 * NB * 68; i += NT) ((float*)h2f)[i] = 0.f;
    if (tid < 64) wlin_s[tid] = (tid < Hs) ? W_lin[tid] : 0.f;
    if (tid == 0) blin_sh = b_lin[0];
    __syncthreads();                   // RACE FIX: zero-fill visible first

    if (tid < NB) {                    // x[0] into parity 1 (read at it=0)
        float xv = x[bg0 + tid];
        u16 hh = bfh_(xv);
        Ah[1][tid * SA + XCOL] = hh;
        Al[1][tid * SA + XCOL] = bfh_(xv - bff_(hh));
    }

    float cc0 = 0.f, cc1 = 0.f, cc2 = 0.f, cc3 = 0.f;
    __syncthreads();                   // staging visible before iter 0

    if (role == 0) {
        // ======================= L1 path =======================
        FragHL bI0 = mkB1(W_hh1, W_ih1, 0 * Hs + jrow, rv, 0, ch);
        FragHL bI1 = mkB1(W_hh1, W_ih1, 0 * Hs + jrow, rv, 1, ch);
        FragHL bF0 = mkB1(W_hh1, W_ih1, 1 * Hs + jrow, rv, 0, ch);
        FragHL bF1 = mkB1(W_hh1, W_ih1, 1 * Hs + jrow, rv, 1, ch);
        FragHL bG0 = mkB1(W_hh1, W_ih1, 2 * Hs + jrow, rv, 0, ch);
        FragHL bG1 = mkB1(W_hh1, W_ih1, 2 * Hs + jrow, rv, 1, ch);
        FragHL bO0 = mkB1(W_hh1, W_ih1, 3 * Hs + jrow, rv, 0, ch);
        FragHL bO1 = mkB1(W_hh1, W_ih1, 3 * Hs + jrow, rv, 1, ch);
        const float bbI = rv ? (b_ih1[0 * Hs + jrow] + b_hh1[0 * Hs + jrow]) : 0.f;
        const float bbF = rv ? (b_ih1[1 * Hs + jrow] + b_hh1[1 * Hs + jrow]) : 0.f;
        const float bbG = rv ? (b_ih1[2 * Hs + jrow] + b_hh1[2 * Hs + jrow]) : 0.f;
        const float bbO = rv ? (b_ih1[3 * Hs + jrow] + b_hh1[3 * Hs + jrow]) : 0.f;

        for (int it = 0; it <= Ts + 1; ++it) {
            const int pR = (it - 1) & 1;
            const int pW = it & 1;
            if (it < Ts) {
                const u16* ph = &Ah[pR][m * SA + ch * 8];
                const u16* pl = &Al[pR][m * SA + ch * 8];
                bf16x8 A0h = *(const bf16x8*)(ph);
                bf16x8 A0l = *(const bf16x8*)(pl);
                bf16x8 A1h = *(const bf16x8*)(ph + 32);
                bf16x8 A1l = *(const bf16x8*)(pl + 32);
                f32x4 aI = {bbI, bbI, bbI, bbI};
                f32x4 aF = {bbF, bbF, bbF, bbF};
                f32x4 aG = {bbG, bbG, bbG, bbG};
                f32x4 aO = {bbO, bbO, bbO, bbO};
                MF(aI, A0h, A0l, bI0)  MF(aF, A0h, A0l, bF0)
                MF(aG, A0h, A0l, bG0)  MF(aO, A0h, A0l, bO0)
                MF(aI, A1h, A1l, bI1)  MF(aF, A1h, A1l, bF1)
                MF(aG, A1h, A1l, bG1)  MF(aO, A1h, A1l, bO1)
                #define E1STEP(RR, CC)                                         \
                {                                                              \
                    float iv = sig_ (aI[RR]);                                  \
                    float fv = sig_ (aF[RR]);                                  \
                    float gv = tanh_(aG[RR]);                                  \
                    float ov = sig_ (aO[RR]);                                  \
                    CC = fmaf(fv, CC, iv * gv);                                \
                    float hv = ov * tanh_(CC);                                 \
                    if (rv) {                                                  \
                        const int b = 4 * ch + RR;                             \
                        u16 hh = bfh_(hv);                                     \
                        Ah[pW][b * SA + jrow] = hh;                            \
                        Al[pW][b * SA + jrow] = bfh_(hv - bff_(hh));           \
                    }                                                          \
                }
                E1STEP(0, cc0) E1STEP(1, cc1) E1STEP(2, cc2) E1STEP(3, cc3)
                #undef E1STEP
            }
            // x[it+1] staging into parity pW (wave 0, 16 lanes)
            if (jg == 0 && lane < NB && (it + 1) < Ts) {
                float xv = xs[it + 1][lane];
                u16 hh = bfh_(xv);
                Ah[pW][lane * SA + XCOL] = hh;
                Al[pW][lane * SA + XCOL] = bfh_(xv - bff_(hh));
            }
            // y[it-2] = W_lin . h2[it-2] + b  (batch = 4*jg + ch)
            if (it >= 2) {
                const float* hp = &h2f[it & 1][4 * jg + ch][0];
                float s = wlin_s[m]      * hp[m]
                        + wlin_s[m + 16] * hp[m + 16]
                        + wlin_s[m + 32] * hp[m + 32]
                        + wlin_s[m + 48] * hp[m + 48];
                s += __shfl_xor(s, 1);
                s += __shfl_xor(s, 2);
                s += __shfl_xor(s, 4);
                s += __shfl_xor(s, 8);
                if (m == 0) out[(bg0 + 4 * jg + ch) * Ts + (it - 2)] = s + blin_sh;
            }
            __syncthreads();
        }
    } else {
        // ======================= L2 path =======================
        FragHL cI0 = mkB2(W_ih2, W_hh2, 0 * Hs + jrow, rv, 0, ch);
        FragHL cI1 = mkB2(W_ih2, W_hh2, 0 * Hs + jrow, rv, 1, ch);
        FragHL cI2 = mkB2(W_ih2, W_hh2, 0 * Hs + jrow, rv, 2, ch);
        FragHL cI3 = mkB2(W_ih2, W_hh2, 0 * Hs + jrow, rv, 3, ch);
        FragHL cF0 = mkB2(W_ih2, W_hh2, 1 * Hs + jrow, rv, 0, ch);
        FragHL cF1 = mkB2(W_ih2, W_hh2, 1 * Hs + jrow, rv, 1, ch);
        FragHL cF2 = mkB2(W_ih2, W_hh2, 1 * Hs + jrow, rv, 2, ch);
        FragHL cF3 = mkB2(W_ih2, W_hh2, 1 * Hs + jrow, rv, 3, ch);
        FragHL cG0 = mkB2(W_ih2, W_hh2, 2 * Hs + jrow, rv, 0, ch);
        FragHL cG1 = mkB2(W_ih2, W_hh2, 2 * Hs + jrow, rv, 1, ch);
        FragHL cG2 = mkB2(W_ih2, W_hh2, 2 * Hs + jrow, rv, 2, ch);
        FragHL cG3 = mkB2(W_ih2, W_hh2, 2 * Hs + jrow, rv, 3, ch);
        FragHL cO0 = mkB2(W_ih2, W_hh2, 3 * Hs + jrow, rv, 0, ch);
        FragHL cO1 = mkB2(W_ih2, W_hh2, 3 * Hs + jrow, rv, 1, ch);
        FragHL cO2 = mkB2(W_ih2, W_hh2, 3 * Hs + jrow, rv, 2, ch);
        FragHL cO3 = mkB2(W_ih2, W_hh2, 3 * Hs + jrow, rv, 3, ch);
        const float bbI = rv ? (b_ih2[0 * Hs + jrow] + b_hh2[0 * Hs + jrow]) : 0.f;
        const float bbF = rv ? (b_ih2[1 * Hs + jrow] + b_hh2[1 * Hs + jrow]) : 0.f;
        const float bbG = rv ? (b_ih2[2 * Hs + jrow] + b_hh2[2 * Hs + jrow]) : 0.f;
        const float bbO = rv ? (b_ih2[3 * Hs + jrow] + b_hh2[3 * Hs + jrow]) : 0.f;

        for (int it = 0; it <= Ts + 1; ++it) {
            const int pR = (it - 1) & 1;
            const int pW = it & 1;
            if (it >= 1 && it <= Ts) {
                const u16* ph = &Ah[pR][m * SA + ch * 8];
                const u16* pl = &Al[pR][m * SA + ch * 8];
                bf16x8 A0h = *(const bf16x8*)(ph);
                bf16x8 A0l = *(const bf16x8*)(pl);
                bf16x8 A1h = *(const bf16x8*)(ph + 32);
                bf16x8 A1l = *(const bf16x8*)(pl + 32);
                bf16x8 A2h = *(const bf16x8*)(ph + 64);
                bf16x8 A2l = *(const bf16x8*)(pl + 64);
                bf16x8 A3h = *(const bf16x8*)(ph + 96);
                bf16x8 A3l = *(const bf16x8*)(pl + 96);
                f32x4 aI = {bbI, bbI, bbI, bbI};
                f32x4 aF = {bbF, bbF, bbF, bbF};
                f32x4 aG = {bbG, bbG, bbG, bbG};
                f32x4 aO = {bbO, bbO, bbO, bbO};
                MF(aI, A0h, A0l, cI0)  MF(aF, A0h, A0l, cF0)
                MF(aG, A0h, A0l, cG0)  MF(aO, A0h, A0l, cO0)
                MF(aI, A1h, A1l, cI1)  MF(aF, A1h, A1l, cF1)
                MF(aG, A1h, A1l, cG1)  MF(aO, A1h, A1l, cO1)
                MF(aI, A2h, A2l, cI2)  MF(aF, A2h, A2l, cF2)
                MF(aG, A2h, A2l, cG2)  MF(aO, A2h, A2l, cO2)
                MF(aI, A3h, A3l, cI3)  MF(aF, A3h, A3l, cF3)
                MF(aG, A3h, A3l, cG3)  MF(aO, A3h, A3l, cO3)
                const int pE = (it - 1) & 1;     // h2f parity for h2[it-1]
                #define E2STEP(RR, CC)                                         \
                {                                                              \
                    float iv = sig_ (aI[RR]);                                  \
                    float fv = sig_ (aF[RR]);                                  \
                    float gv = tanh_(aG[RR]);                                  \
                    float ov = sig_ (aO[RR]);                                  \
                    CC = fmaf(fv, CC, iv * gv);                                \
                    float hv = ov * tanh_(CC);                                 \
                    if (rv) {                                                  \
                        const int b = 4 * ch + RR;                             \
                        u16 hh = bfh_(hv);                                     \
                        Ah[pW][b * SA + H2COL + jrow] = hh;                    \
                        Al[pW][b * SA + H2COL + jrow] = bfh_(hv - bff_(hh));   \
                        h2f[pE][b][jrow] = hv;                                 \
                    }                                                          \
                }
                E2STEP(0, cc0) E2STEP(1, cc1) E2STEP(2, cc2) E2STEP(3, cc3)
                #undef E2STEP
            }
            __syncthreads();
        }
    }
}

extern "C" void kernel_launch(void* const* d_in, const int* in_sizes, int n_in,
                              void* d_out, int out_size, void* d_ws, size_t ws_size,
                              hipStream_t stream) {
    const float* x     = (const float*)d_in[0];
    const float* W_ih1 = (const float*)d_in[1];
    const float* W_hh1 = (const float*)d_in[2];
    const float* b_ih1 = (const float*)d_in[3];
    const float* b_hh1 = (const float*)d_in[4];
    const float* W_ih2 = (const float*)d_in[5];
    const float* W_hh2 = (const float*)d_in[6];
    const float* b_ih2 = (const float*)d_in[7];
    const float* b_hh2 = (const float*)d_in[8];
    const float* W_lin = (const float*)d_in[9];
    const float* b_lin = (const float*)d_in[10];
    float* out = (float*)d_out;

    lstm2_kernel<<<Bs / NB, NT, 0, stream>>>(
        x, W_ih1, W_hh1, b_ih1, b_hh1,
        W_ih2, W_hh2, b_ih2, b_hh2, W_lin, b_lin, out);
}

// Round 7
// 1033.295 us; speedup vs baseline: 1.1318x; 1.0036x over previous
//
#include <hip/hip_runtime.h>

// LSTM_26912265077001: 2-layer LSTM (H=51, IN=1), T=512, B=1024, fp32.
//
// V8 = V7 + amdgpu_waves_per_eu(2,2) to stop the backend from targeting
// 4 waves/EU (VGPR=128) and sinking/spilling the weight fragments.
// V7 post-mortem: VGPR_Count=128 < the ~200 the L2 path needs (B-frags
// alone = 128 VGPRs) -> weights re-fetched every iter, MfmaUtil 6.2%,
// ~4630 cy/iter. Occupancy insight: grid is 64 blocks / 256 CUs -> 1
// block/CU = 2 waves/SIMD REGARDLESS of VGPR 128 vs 256, so the
// compiler's 128-reg choice bought zero occupancy. Pin waves/EU to
// [2,2] -> VGPR budget 256 -> fragments stay register-resident.
//
// Design (V5/V6, m89-verified MFMA maps):
//  - NB=16 batches/block, 64 blocks, 8 waves: waves 0-3 L1 (j-groups),
//    waves 4-7 L2. Gate-aligned B tiles: for j-group j0, tiles are gate
//    rows {g*51 + j0 + m}; after MFMA lane (m,ch) reg r holds the full
//    (i,f,g,o) quad for (batch 4ch+r, unit j0+m) -> elementwise in regs.
//  - A operand [h1(0..50) | x(51) | 0 | h2(64..114) | 0] bf16 hi/lo,
//    parity double-buffered. L1 K=64 (2 ksteps), L2 K=128 (4 ksteps).
//  - 3-term split product (AhBl + AlBh + AhBh), 1 barrier/iter.
//  - ALL fragments individually NAMED, loops hand-unrolled (no arrays,
//    no scratch demotion). Role paths = two separate main loops with
//    equal barrier counts.
//  - Init: zero-fill -> barrier -> x[0] staging -> barrier (V7 race fix).
//  - Pipeline: it: L1->h1[it] (it<Ts); L2->h2[it-1] (1<=it<=Ts);
//    y[it-2] (it>=2); loop to Ts+1 to drain.

#define Hs    51
#define Ts    512
#define Bs    1024
#define NB    16
#define NT    512
#define SA    136        // A row stride in ushorts (272B, 16B-aligned)
#define XCOL  51
#define H2COL 64

typedef __attribute__((ext_vector_type(8))) short bf16x8;
typedef __attribute__((ext_vector_type(4))) float f32x4;
typedef unsigned short u16;

__device__ __forceinline__ float sig_(float x)  { return 1.0f / (1.0f + __expf(-x)); }
__device__ __forceinline__ float tanh_(float x) { float e = __expf(2.0f * x); return 1.0f - 2.0f / (e + 1.0f); }
__device__ __forceinline__ u16 bfh_(float x) {   // fp32 -> bf16 (RNE)
    unsigned u = __float_as_uint(x);
    return (u16)((u + 0x7FFFu + ((u >> 16) & 1u)) >> 16);
}
__device__ __forceinline__ float bff_(u16 h) { return __uint_as_float(((unsigned)h) << 16); }

struct FragHL { bf16x8 h; bf16x8 l; };

// B1 fragment: row of [W_hh1 | W_ih1] at K-step ks, chunk ch.
__device__ __forceinline__ FragHL mkB1(const float* __restrict__ Whh1,
                                       const float* __restrict__ Wih1,
                                       int row, bool rv, int ks, int ch) {
    bf16x8 h = {0,0,0,0,0,0,0,0}, l = {0,0,0,0,0,0,0,0};
    #pragma unroll
    for (int j = 0; j < 8; ++j) {
        const int k = ks * 32 + ch * 8 + j;
        float v = 0.f;
        if (rv) {
            if (k < Hs)         v = Whh1[row * Hs + k];
            else if (k == XCOL) v = Wih1[row];
        }
        u16 hh = bfh_(v);
        h[j] = (short)hh;
        l[j] = (short)bfh_(v - bff_(hh));
    }
    FragHL r; r.h = h; r.l = l; return r;
}

// B2 fragment: row of [W_ih2 | 0 | W_hh2 | 0] at K-step ks, chunk ch.
__device__ __forceinline__ FragHL mkB2(const float* __restrict__ Wih2,
                                       const float* __restrict__ Whh2,
                                       int row, bool rv, int ks, int ch) {
    bf16x8 h = {0,0,0,0,0,0,0,0}, l = {0,0,0,0,0,0,0,0};
    #pragma unroll
    for (int j = 0; j < 8; ++j) {
        const int k = ks * 32 + ch * 8 + j;
        float v = 0.f;
        if (rv) {
            if (k < Hs)                              v = Wih2[row * Hs + k];
            else if (k >= H2COL && k < H2COL + Hs)   v = Whh2[row * Hs + (k - H2COL)];
        }
        u16 hh = bfh_(v);
        h[j] = (short)hh;
        l[j] = (short)bfh_(v - bff_(hh));
    }
    FragHL r; r.h = h; r.l = l; return r;
}

// 3-term split-product accumulate, same term order as V5 (numerics identical)
#define MF(ACC, AFH, AFL, BF)                                                  \
    ACC = __builtin_amdgcn_mfma_f32_16x16x32_bf16(AFH, (BF).l, ACC, 0, 0, 0);  \
    ACC = __builtin_amdgcn_mfma_f32_16x16x32_bf16(AFL, (BF).h, ACC, 0, 0, 0);  \
    ACC = __builtin_amdgcn_mfma_f32_16x16x32_bf16(AFH, (BF).h, ACC, 0, 0, 0);

__global__ __launch_bounds__(NT)
__attribute__((amdgpu_waves_per_eu(2, 2)))
void lstm2_kernel(
    const float* __restrict__ x,      // (T, B, 1)
    const float* __restrict__ W_ih1,  // (204, 1)
    const float* __restrict__ W_hh1,  // (204, 51)
    const float* __restrict__ b_ih1,  // (204,)
    const float* __restrict__ b_hh1,  // (204,)
    const float* __restrict__ W_ih2,  // (204, 51)
    const float* __restrict__ W_hh2,  // (204, 51)
    const float* __restrict__ b_ih2,  // (204,)
    const float* __restrict__ b_hh2,  // (204,)
    const float* __restrict__ W_lin,  // (1, 51)
    const float* __restrict__ b_lin,  // (1,)
    float* __restrict__ out)          // (B, T)
{
    __shared__ __align__(16) u16   Ah[2][NB * SA];
    __shared__ __align__(16) u16   Al[2][NB * SA];
    __shared__ __align__(16) float xs[Ts][NB];
    __shared__ __align__(16) float h2f[2][NB][68];
    __shared__ __align__(16) float wlin_s[64];
    __shared__ float blin_sh;

    const int tid  = threadIdx.x;
    const int lane = tid & 63;
    const int wv   = tid >> 6;         // 0..7
    const int role = wv >> 2;          // 0 = L1, 1 = L2
    const int jg   = wv & 3;
    const int m    = lane & 15;
    const int ch   = lane >> 4;
    const int bg0  = blockIdx.x * NB;
    const int  jrow = jg * 16 + m;     // unit index (valid < 51)
    const bool rv   = jrow < Hs;

    // ---- one-time init: zero / preload (NO staging writes yet) ----
    for (int i = tid; i < Ts * NB; i += NT) {
        int t = i >> 4, b = i & 15;
        xs[t][b] = x[t * Bs + bg0 + b];
    }
    for (int i = tid; i < 2 * NB * SA; i += NT) {
        ((u16*)Ah)[i] = 0;
        ((u16*)Al)[i] = 0;
    }
    for (int i = tid; i < 2 * NB * 68; i += NT) ((float*)h2f)[i] = 0.f;
    if (tid < 64) wlin_s[tid] = (tid < Hs) ? W_lin[tid] : 0.f;
    if (tid == 0) blin_sh = b_lin[0];
    __syncthreads();                   // zero-fill visible first (V7 race fix)

    if (tid < NB) {                    // x[0] into parity 1 (read at it=0)
        float xv = x[bg0 + tid];
        u16 hh = bfh_(xv);
        Ah[1][tid * SA + XCOL] = hh;
        Al[1][tid * SA + XCOL] = bfh_(xv - bff_(hh));
    }

    float cc0 = 0.f, cc1 = 0.f, cc2 = 0.f, cc3 = 0.f;
    __syncthreads();                   // staging visible before iter 0

    if (role == 0) {
        // ======================= L1 path =======================
        FragHL bI0 = mkB1(W_hh1, W_ih1, 0 * Hs + jrow, rv, 0, ch);
        FragHL bI1 = mkB1(W_hh1, W_ih1, 0 * Hs + jrow, rv, 1, ch);
        FragHL bF0 = mkB1(W_hh1, W_ih1, 1 * Hs + jrow, rv, 0, ch);
        FragHL bF1 = mkB1(W_hh1, W_ih1, 1 * Hs + jrow, rv, 1, ch);
        FragHL bG0 = mkB1(W_hh1, W_ih1, 2 * Hs + jrow, rv, 0, ch);
        FragHL bG1 = mkB1(W_hh1, W_ih1, 2 * Hs + jrow, rv, 1, ch);
        FragHL bO0 = mkB1(W_hh1, W_ih1, 3 * Hs + jrow, rv, 0, ch);
        FragHL bO1 = mkB1(W_hh1, W_ih1, 3 * Hs + jrow, rv, 1, ch);
        const float bbI = rv ? (b_ih1[0 * Hs + jrow] + b_hh1[0 * Hs + jrow]) : 0.f;
        const float bbF = rv ? (b_ih1[1 * Hs + jrow] + b_hh1[1 * Hs + jrow]) : 0.f;
        const float bbG = rv ? (b_ih1[2 * Hs + jrow] + b_hh1[2 * Hs + jrow]) : 0.f;
        const float bbO = rv ? (b_ih1[3 * Hs + jrow] + b_hh1[3 * Hs + jrow]) : 0.f;

        for (int it = 0; it <= Ts + 1; ++it) {
            const int pR = (it - 1) & 1;
            const int pW = it & 1;
            if (it < Ts) {
                const u16* ph = &Ah[pR][m * SA + ch * 8];
                const u16* pl = &Al[pR][m * SA + ch * 8];
                bf16x8 A0h = *(const bf16x8*)(ph);
                bf16x8 A0l = *(const bf16x8*)(pl);
                bf16x8 A1h = *(const bf16x8*)(ph + 32);
                bf16x8 A1l = *(const bf16x8*)(pl + 32);
                f32x4 aI = {bbI, bbI, bbI, bbI};
                f32x4 aF = {bbF, bbF, bbF, bbF};
                f32x4 aG = {bbG, bbG, bbG, bbG};
                f32x4 aO = {bbO, bbO, bbO, bbO};
                MF(aI, A0h, A0l, bI0)  MF(aF, A0h, A0l, bF0)
                MF(aG, A0h, A0l, bG0)  MF(aO, A0h, A0l, bO0)
                MF(aI, A1h, A1l, bI1)  MF(aF, A1h, A1l, bF1)
                MF(aG, A1h, A1l, bG1)  MF(aO, A1h, A1l, bO1)
                #define E1STEP(RR, CC)                                         \
                {                                                              \
                    float iv = sig_ (aI[RR]);                                  \
                    float fv = sig_ (aF[RR]);                                  \
                    float gv = tanh_(aG[RR]);                                  \
                    float ov = sig_ (aO[RR]);                                  \
                    CC = fmaf(fv, CC, iv * gv);                                \
                    float hv = ov * tanh_(CC);                                 \
                    if (rv) {                                                  \
                        const int b = 4 * ch + RR;                             \
                        u16 hh = bfh_(hv);                                     \
                        Ah[pW][b * SA + jrow] = hh;                            \
                        Al[pW][b * SA + jrow] = bfh_(hv - bff_(hh));           \
                    }                                                          \
                }
                E1STEP(0, cc0) E1STEP(1, cc1) E1STEP(2, cc2) E1STEP(3, cc3)
                #undef E1STEP
            }
            // x[it+1] staging into parity pW (wave 0, 16 lanes)
            if (jg == 0 && lane < NB && (it + 1) < Ts) {
                float xv = xs[it + 1][lane];
                u16 hh = bfh_(xv);
                Ah[pW][lane * SA + XCOL] = hh;
                Al[pW][lane * SA + XCOL] = bfh_(xv - bff_(hh));
            }
            // y[it-2] = W_lin . h2[it-2] + b  (batch = 4*jg + ch)
            if (it >= 2) {
                const float* hp = &h2f[it & 1][4 * jg + ch][0];
                float s = wlin_s[m]      * hp[m]
                        + wlin_s[m + 16] * hp[m + 16]
                        + wlin_s[m + 32] * hp[m + 32]
                        + wlin_s[m + 48] * hp[m + 48];
                s += __shfl_xor(s, 1);
                s += __shfl_xor(s, 2);
                s += __shfl_xor(s, 4);
                s += __shfl_xor(s, 8);
                if (m == 0) out[(bg0 + 4 * jg + ch) * Ts + (it - 2)] = s + blin_sh;
            }
            __syncthreads();
        }
    } else {
        // ======================= L2 path =======================
        FragHL cI0 = mkB2(W_ih2, W_hh2, 0 * Hs + jrow, rv, 0, ch);
        FragHL cI1 = mkB2(W_ih2, W_hh2, 0 * Hs + jrow, rv, 1, ch);
        FragHL cI2 = mkB2(W_ih2, W_hh2, 0 * Hs + jrow, rv, 2, ch);
        FragHL cI3 = mkB2(W_ih2, W_hh2, 0 * Hs + jrow, rv, 3, ch);
        FragHL cF0 = mkB2(W_ih2, W_hh2, 1 * Hs + jrow, rv, 0, ch);
        FragHL cF1 = mkB2(W_ih2, W_hh2, 1 * Hs + jrow, rv, 1, ch);
        FragHL cF2 = mkB2(W_ih2, W_hh2, 1 * Hs + jrow, rv, 2, ch);
        FragHL cF3 = mkB2(W_ih2, W_hh2, 1 * Hs + jrow, rv, 3, ch);
        FragHL cG0 = mkB2(W_ih2, W_hh2, 2 * Hs + jrow, rv, 0, ch);
        FragHL cG1 = mkB2(W_ih2, W_hh2, 2 * Hs + jrow, rv, 1, ch);
        FragHL cG2 = mkB2(W_ih2, W_hh2, 2 * Hs + jrow, rv, 2, ch);
        FragHL cG3 = mkB2(W_ih2, W_hh2, 2 * Hs + jrow, rv, 3, ch);
        FragHL cO0 = mkB2(W_ih2, W_hh2, 3 * Hs + jrow, rv, 0, ch);
        FragHL cO1 = mkB2(W_ih2, W_hh2, 3 * Hs + jrow, rv, 1, ch);
        FragHL cO2 = mkB2(W_ih2, W_hh2, 3 * Hs + jrow, rv, 2, ch);
        FragHL cO3 = mkB2(W_ih2, W_hh2, 3 * Hs + jrow, rv, 3, ch);
        const float bbI = rv ? (b_ih2[0 * Hs + jrow] + b_hh2[0 * Hs + jrow]) : 0.f;
        const float bbF = rv ? (b_ih2[1 * Hs + jrow] + b_hh2[1 * Hs + jrow]) : 0.f;
        const float bbG = rv ? (b_ih2[2 * Hs + jrow] + b_hh2[2 * Hs + jrow]) : 0.f;
        const float bbO = rv ? (b_ih2[3 * Hs + jrow] + b_hh2[3 * Hs + jrow]) : 0.f;

        for (int it = 0; it <= Ts + 1; ++it) {
            const int pR = (it - 1) & 1;
            const int pW = it & 1;
            if (it >= 1 && it <= Ts) {
                const u16* ph = &Ah[pR][m * SA + ch * 8];
                const u16* pl = &Al[pR][m * SA + ch * 8];
                bf16x8 A0h = *(const bf16x8*)(ph);
                bf16x8 A0l = *(const bf16x8*)(pl);
                bf16x8 A1h = *(const bf16x8*)(ph + 32);
                bf16x8 A1l = *(const bf16x8*)(pl + 32);
                bf16x8 A2h = *(const bf16x8*)(ph + 64);
                bf16x8 A2l = *(const bf16x8*)(pl + 64);
                bf16x8 A3h = *(const bf16x8*)(ph + 96);
                bf16x8 A3l = *(const bf16x8*)(pl + 96);
                f32x4 aI = {bbI, bbI, bbI, bbI};
                f32x4 aF = {bbF, bbF, bbF, bbF};
                f32x4 aG = {bbG, bbG, bbG, bbG};
                f32x4 aO = {bbO, bbO, bbO, bbO};
                MF(aI, A0h, A0l, cI0)  MF(aF, A0h, A0l, cF0)
                MF(aG, A0h, A0l, cG0)  MF(aO, A0h, A0l, cO0)
                MF(aI, A1h, A1l, cI1)  MF(aF, A1h, A1l, cF1)
                MF(aG, A1h, A1l, cG1)  MF(aO, A1h, A1l, cO1)
                MF(aI, A2h, A2l, cI2)  MF(aF, A2h, A2l, cF2)
                MF(aG, A2h, A2l, cG2)  MF(aO, A2h, A2l, cO2)
                MF(aI, A3h, A3l, cI3)  MF(aF, A3h, A3l, cF3)
                MF(aG, A3h, A3l, cG3)  MF(aO, A3h, A3l, cO3)
                const int pE = (it - 1) & 1;     // h2f parity for h2[it-1]
                #define E2STEP(RR, CC)                                         \
                {                                                              \
                    float iv = sig_ (aI[RR]);                                  \
                    float fv = sig_ (aF[RR]);                                  \
                    float gv = tanh_(aG[RR]);                                  \
                    float ov = sig_ (aO[RR]);                                  \
                    CC = fmaf(fv, CC, iv * gv);                                \
                    float hv = ov * tanh_(CC);                                 \
                    if (rv) {                                                  \
                        const int b = 4 * ch + RR;                             \
                        u16 hh = bfh_(hv);                                     \
                        Ah[pW][b * SA + H2COL + jrow] = hh;                    \
                        Al[pW][b * SA + H2COL + jrow] = bfh_(hv - bff_(hh));   \
                        h2f[pE][b][jrow] = hv;                                 \
                    }                                                          \
                }
                E2STEP(0, cc0) E2STEP(1, cc1) E2STEP(2, cc2) E2STEP(3, cc3)
                #undef E2STEP
            }
            __syncthreads();
        }
    }
}

extern "C" void kernel_launch(void* const* d_in, const int* in_sizes, int n_in,
                              void* d_out, int out_size, void* d_ws, size_t ws_size,
                              hipStream_t stream) {
    const float* x     = (const float*)d_in[0];
    const float* W_ih1 = (const float*)d_in[1];
    const float* W_hh1 = (const float*)d_in[2];
    const float* b_ih1 = (const float*)d_in[3];
    const float* b_hh1 = (const float*)d_in[4];
    const float* W_ih2 = (const float*)d_in[5];
    const float* W_hh2 = (const float*)d_in[6];
    const float* b_ih2 = (const float*)d_in[7];
    const float* b_hh2 = (const float*)d_in[8];
    const float* W_lin = (const float*)d_in[9];
    const float* b_lin = (const float*)d_in[10];
    float* out = (float*)d_out;

    lstm2_kernel<<<Bs / NB, NT, 0, stream>>>(
        x, W_ih1, W_hh1, b_ih1, b_hh1,
        W_ih2, W_hh2, b_ih2, b_hh2, W_lin, b_lin, out);
}